// Round 1
// baseline (74.176 us; speedup 1.0000x reference)
//
#include <hip/hip_runtime.h>

#define SPAN 20
#define REPEAT 90

// pred, gt: [4, 1, 512, 512] f32. h_offsets, w_offsets: [90] i32.
// out: scalar f32 = mean |l2norm(pred_rd) - l2norm(gt_rd)| over [B,Hb,Wb,R].

__global__ __launch_bounds__(256) void rd_loss_kernel(
    const float* __restrict__ pred, const float* __restrict__ gt,
    const int* __restrict__ hoff, const int* __restrict__ woff,
    float* __restrict__ out)
{
    constexpr int W  = 512;
    constexpr int Wb = 512 - 2 * SPAN;   // 472

    __shared__ int soff[REPEAT];
    const int t = threadIdx.x;
    if (t < REPEAT) soff[t] = hoff[t] * W + woff[t];
    __syncthreads();

    const int j = blockIdx.x * 256 + t;   // 0..471 (upper block partially masked)
    const int i = blockIdx.y;             // 0..471
    const int b = blockIdx.z;             // 0..3

    float lsum = 0.0f;
    if (j < Wb) {
        const int baseIdx = (b * 512 + (SPAN + i)) * W + (SPAN + j);
        const float pb = pred[baseIdx];
        const float gb = gt[baseIdx];

        float ssp = 0.0f, ssg = 0.0f;
        #pragma unroll 10
        for (int r = 0; r < REPEAT; ++r) {
            const int idx = baseIdx + soff[r];
            const float dp = pb - pred[idx];
            const float dg = gb - gt[idx];
            ssp = fmaf(dp, dp, ssp);
            ssg = fmaf(dg, dg, ssg);
        }

        const float pn = sqrtf(ssp);
        const float gn = sqrtf(ssg);
        const float invp = (pn == 0.0f) ? 1.0f : 1.0f / pn;
        const float invg = (gn == 0.0f) ? 1.0f : 1.0f / gn;

        #pragma unroll 10
        for (int r = 0; r < REPEAT; ++r) {
            const int idx = baseIdx + soff[r];
            const float dp = pb - pred[idx];
            const float dg = gb - gt[idx];
            lsum += fabsf(dp * invp - dg * invg);
        }
    }

    // wave (64-lane) shuffle reduction
    #pragma unroll
    for (int o = 32; o > 0; o >>= 1) lsum += __shfl_down(lsum, o, 64);

    __shared__ float wsum[4];
    const int lane = t & 63;
    const int wid  = t >> 6;
    if (lane == 0) wsum[wid] = lsum;
    __syncthreads();

    if (t == 0) {
        const float s = wsum[0] + wsum[1] + wsum[2] + wsum[3];
        constexpr float scale = 1.0f / (4.0f * 472.0f * 472.0f * 90.0f);
        atomicAdd(out, s * scale);
    }
}

extern "C" void kernel_launch(void* const* d_in, const int* in_sizes, int n_in,
                              void* d_out, int out_size, void* d_ws, size_t ws_size,
                              hipStream_t stream) {
    const float* pred = (const float*)d_in[0];
    const float* gt   = (const float*)d_in[1];
    const int* hoff   = (const int*)d_in[2];
    const int* woff   = (const int*)d_in[3];
    float* out = (float*)d_out;

    // Harness poisons d_out once and never re-poisons between graph replays:
    // zero it on-stream every call (graph-capturable).
    hipMemsetAsync(out, 0, sizeof(float), stream);

    dim3 grid((472 + 255) / 256, 472, 4);   // (2, 472, 4)
    rd_loss_kernel<<<grid, 256, 0, stream>>>(pred, gt, hoff, woff, out);
}

// Round 2
// 46.564 us; speedup vs baseline: 1.5930x; 1.5930x over previous
//
#include <hip/hip_runtime.h>

#define SPAN 20
#define REPEAT 90

// pred, gt: [4, 1, 512, 512] f32. h_offsets, w_offsets: [90] i32.
// out: scalar f32 = mean |l2norm(pred_rd) - l2norm(gt_rd)| over [B,Hb,Wb,R].

constexpr int W  = 512;
constexpr int Wb = 472;           // 512 - 2*SPAN
constexpr int TJ = 64;            // output tile width  (j)
constexpr int TI = 8;             // output tile height (i); 472/8 = 59 exact
constexpr int TW = TJ + 2 * SPAN; // 104 input tile width
constexpr int TH = TI + 2 * SPAN; // 48  input tile height

__global__ __launch_bounds__(256) void rd_loss_kernel(
    const float* __restrict__ pred, const float* __restrict__ gt,
    const int* __restrict__ hoff, const int* __restrict__ woff,
    float* __restrict__ out)
{
    // p/g interleaved so one ds_read_b64 serves both arrays: 48*104*8 = 39936 B
    __shared__ float2 tile[TH * TW];
    __shared__ float wsum[4];

    const int t  = threadIdx.x;
    const int bx = blockIdx.x;    // 0..7   j-tile
    const int by = blockIdx.y;    // 0..58  i-tile
    const int b  = blockIdx.z;    // 0..3   batch
    const int I0 = by * TI;
    const int J0 = bx * TJ;

    const float* pb_ = pred + b * (W * W);
    const float* gb_ = gt   + b * (W * W);

    // ---- stage input tile (rows I0..I0+47 always <= 511; cols clamped) ----
    for (int e = t; e < TH * TW; e += 256) {
        const int row = e / TW;           // const-div -> magic mul
        const int col = e - row * TW;
        const int gr  = I0 + row;                      // <= 511 always
        int gc        = J0 + col; gc = gc < 511 ? gc : 511;
        const int gi  = gr * W + gc;
        tile[e] = make_float2(pb_[gi], gb_[gi]);
    }
    __syncthreads();

    // ---- each thread owns 2 pixels: (ii, jj) and (ii+4, jj) ----
    const int jj  = t & 63;
    const int wid = t >> 6;               // 0..3
    const int j   = J0 + jj;
    const bool valid = (j < Wb);          // i is always valid (59*8 = 472)

    const int base0 = (SPAN + wid) * TW + (SPAN + jj);
    const float2 c0 = tile[base0];
    const float2 c1 = tile[base0 + 4 * TW];

    // pass 1: sum of squares
    float ssp0 = 0.f, ssg0 = 0.f, ssp1 = 0.f, ssg1 = 0.f;
    #pragma unroll 15
    for (int r = 0; r < REPEAT; ++r) {
        const int off = hoff[r] * TW + woff[r];        // uniform -> s_load + SALU
        const float2 v0 = tile[base0 + off];
        const float2 v1 = tile[base0 + 4 * TW + off];  // same vaddr, offset:3328
        const float dp0 = c0.x - v0.x, dg0 = c0.y - v0.y;
        const float dp1 = c1.x - v1.x, dg1 = c1.y - v1.y;
        ssp0 = fmaf(dp0, dp0, ssp0); ssg0 = fmaf(dg0, dg0, ssg0);
        ssp1 = fmaf(dp1, dp1, ssp1); ssg1 = fmaf(dg1, dg1, ssg1);
    }

    const float pn0 = sqrtf(ssp0), gn0 = sqrtf(ssg0);
    const float pn1 = sqrtf(ssp1), gn1 = sqrtf(ssg1);
    const float invp0 = (pn0 == 0.f) ? 1.f : 1.f / pn0;
    const float invg0 = (gn0 == 0.f) ? 1.f : 1.f / gn0;
    const float invp1 = (pn1 == 0.f) ? 1.f : 1.f / pn1;
    const float invg1 = (gn1 == 0.f) ? 1.f : 1.f / gn1;

    // pass 2: sum |dp*invp - dg*invg|
    float l0 = 0.f, l1 = 0.f;
    #pragma unroll 15
    for (int r = 0; r < REPEAT; ++r) {
        const int off = hoff[r] * TW + woff[r];
        const float2 v0 = tile[base0 + off];
        const float2 v1 = tile[base0 + 4 * TW + off];
        const float dp0 = c0.x - v0.x, dg0 = c0.y - v0.y;
        const float dp1 = c1.x - v1.x, dg1 = c1.y - v1.y;
        l0 += fabsf(fmaf(dp0, invp0, -(dg0 * invg0)));
        l1 += fabsf(fmaf(dp1, invp1, -(dg1 * invg1)));
    }

    float lsum = valid ? (l0 + l1) : 0.f;

    // ---- reduction: wave shuffle -> LDS -> one atomic per block ----
    #pragma unroll
    for (int o = 32; o > 0; o >>= 1) lsum += __shfl_down(lsum, o, 64);

    const int lane = t & 63;
    if (lane == 0) wsum[wid] = lsum;
    __syncthreads();

    if (t == 0) {
        const float s = wsum[0] + wsum[1] + wsum[2] + wsum[3];
        constexpr float scale = 1.0f / (4.0f * 472.0f * 472.0f * 90.0f);
        atomicAdd(out, s * scale);
    }
}

extern "C" void kernel_launch(void* const* d_in, const int* in_sizes, int n_in,
                              void* d_out, int out_size, void* d_ws, size_t ws_size,
                              hipStream_t stream) {
    const float* pred = (const float*)d_in[0];
    const float* gt   = (const float*)d_in[1];
    const int* hoff   = (const int*)d_in[2];
    const int* woff   = (const int*)d_in[3];
    float* out = (float*)d_out;

    // Harness poisons d_out once and never re-poisons between graph replays:
    // zero it on-stream every call (graph-capturable).
    hipMemsetAsync(out, 0, sizeof(float), stream);

    dim3 grid(8, 59, 4);   // (472/64 ceil, 472/8, B)
    rd_loss_kernel<<<grid, 256, 0, stream>>>(pred, gt, hoff, woff, out);
}